// Round 19
// baseline (130.592 us; speedup 1.0000x reference)
//
#include <hip/hip_runtime.h>
#include <hip/hip_fp16.h>

// SSIM loss, packed-f16 row-sweep, fully independent waves, ROWS=32.
// Round-19 change vs round 14 (best, 59.6us): outer loop steps 22 = two
// 11-phase groups, making the double-buffer index cur COMPILE-TIME in every
// unrolled body (group A: cur=ph&1, group B: cur=(ph&1)^1). All LDS reads/
// writes become base-reg + immediate-offset (no per-iter buffer-select
// address VALU). Math and DS op count byte-identical to round 14.

#define ROWS 32
#define NIT  (ROWS + 10)         // 42 staged rows per strip
#define NSTRIP 3072              // 48 img * 16 row-bands * 4 col-strips
#define NBLK  (NSTRIP / 4)       // 768 blocks
#define NPIX  12582912.0

static __device__ __forceinline__ unsigned fun16(unsigned hi, unsigned lo) {
    return __builtin_amdgcn_alignbit(hi, lo, 16);   // v_alignbit_b32
}
static __device__ __forceinline__ unsigned h2u(__half2 v) {
    unsigned u; __builtin_memcpy(&u, &v, 4); return u;
}
static __device__ __forceinline__ __half2 u2h(unsigned u) {
    __half2 v; __builtin_memcpy(&v, &u, 4); return v;
}

__global__ __launch_bounds__(256, 4) void ssim_static_kernel(
    const float* __restrict__ X, const float* __restrict__ Y,
    float* __restrict__ partial)
{
    // [wave][map][dbuf][word]; word i = half2 (x[cs-6+2i], x[cs-5+2i]); 4608 B
    __shared__ unsigned sbw[4][2][2][72];

    const int tid  = threadIdx.x;
    const int lane = tid & 63;
    const int w    = tid >> 6;
    const int sid  = blockIdx.x * 4 + w;
    const int img  = sid >> 6;          // 16 bands * 4 strips = 64
    const int rb   = (sid >> 2) & 15;
    const int cs   = (sid & 3) << 7;    // strip col start
    const int r0   = rb * ROWS;

    const float* __restrict__ Xi = X + (size_t)img * (512 * 512);
    const float* __restrict__ Yi = Y + (size_t)img * (512 * 512);

    // Gaussian weights (matches jnp construction)
    float g[11];
    {
        float s = 0.f;
        #pragma unroll
        for (int i = 0; i < 11; ++i) {
            float d = (float)(i - 5);
            float e = expf(-d * d * (1.0f / 4.5f));
            g[i] = e; s += e;
        }
        float inv = 1.0f / s;
        #pragma unroll
        for (int i = 0; i < 11; ++i) g[i] *= inv;
    }
    __half2 w2[11];
    #pragma unroll
    for (int i = 0; i < 11; ++i) w2[i] = __float2half2_rn(g[i]);

    const int c2 = cs + 2 * lane;       // own 2 cols (always in-image)

    // halo duty: lanes 48-53 -> map0 words {0,1,2,67,68,69}; 56-61 -> map1
    int hq = -1, hm = 0;
    if (lane >= 48 && lane < 54)      { hq = lane - 48; hm = 0; }
    else if (lane >= 56 && lane < 62) { hq = lane - 56; hm = 1; }
    const int  hwd = (hq < 0) ? 0 : (hq < 3 ? hq : 64 + hq);
    const int  hc  = cs - 6 + 2 * hwd;
    const bool hok = (hq >= 0) && ((unsigned)hc < 512u);
    const float* hbase = hm ? Yi : Xi;

    float2 nvx, nvy, nvh;
    #define STAGE_LOAD(J)                                                    \
        {                                                                    \
            int gr = r0 - 5 + (J);                                           \
            nvx = make_float2(0.f, 0.f); nvy = nvx; nvh = nvx;               \
            if ((unsigned)gr < 512u) {                                       \
                const float* xr = Xi + (size_t)gr * 512;                     \
                const float* yr = Yi + (size_t)gr * 512;                     \
                nvx = *(const float2*)(xr + c2);                             \
                nvy = *(const float2*)(yr + c2);                             \
                if (hok) nvh = *(const float2*)(hbase + (size_t)gr * 512 + hc); \
            }                                                                \
        }
    #define STAGE_WRITE(BUF)                                                 \
        {                                                                    \
            sbw[w][0][BUF][3 + lane] = h2u(__floats2half2_rn(nvx.x, nvx.y)); \
            sbw[w][1][BUF][3 + lane] = h2u(__floats2half2_rn(nvy.x, nvy.y)); \
            if (hq >= 0) sbw[w][hm][BUF][hwd] = h2u(__floats2half2_rn(nvh.x, nvh.y)); \
        }

    // full row-iteration body; PHC and CURC are compile-time after unroll
    #define BODY(J, PHC, CURC)                                               \
        if ((J) < NIT) {                                                     \
            if ((J) + 1 < NIT) STAGE_LOAD((J) + 1);                          \
            unsigned Dx[7], Dy[7];                                           \
            _Pragma("unroll")                                                \
            for (int k2 = 0; k2 < 7; ++k2) Dx[k2] = sbw[w][0][CURC][lane + k2]; \
            _Pragma("unroll")                                                \
            for (int k2 = 0; k2 < 7; ++k2) Dy[k2] = sbw[w][1][CURC][lane + k2]; \
            __half2 hx, hy, hxx, hyy, hxy;                                   \
            {                                                                \
                const __half2 xk = u2h(fun16(Dx[1], Dx[0]));                 \
                const __half2 yk = u2h(fun16(Dy[1], Dy[0]));                 \
                const __half2 wx = __hmul2(w2[0], xk);                       \
                const __half2 wy = __hmul2(w2[0], yk);                       \
                hx = wx; hy = wy;                                            \
                hxx = __hmul2(wx, xk);                                       \
                hyy = __hmul2(wy, yk);                                       \
                hxy = __hmul2(wx, yk);                                       \
            }                                                                \
            _Pragma("unroll")                                                \
            for (int k = 1; k < 11; ++k) {                                   \
                unsigned ux, uy;                                             \
                if (k & 1) { ux = Dx[(k + 1) >> 1]; uy = Dy[(k + 1) >> 1]; } \
                else       { ux = fun16(Dx[(k >> 1) + 1], Dx[k >> 1]);       \
                             uy = fun16(Dy[(k >> 1) + 1], Dy[k >> 1]); }     \
                const __half2 xk = u2h(ux), yk = u2h(uy);                    \
                const __half2 wx = __hmul2(w2[k], xk);                       \
                const __half2 wy = __hmul2(w2[k], yk);                       \
                hx  = __hadd2(hx, wx);                                       \
                hy  = __hadd2(hy, wy);                                       \
                hxx = __hfma2(wx, xk, hxx);                                  \
                hyy = __hfma2(wy, yk, hyy);                                  \
                hxy = __hfma2(wx, yk, hxy);                                  \
            }                                                                \
            ring[0][PHC] = hx;  ring[1][PHC] = hy;                           \
            ring[2][PHC] = hxx; ring[3][PHC] = hyy; ring[4][PHC] = hxy;      \
            if ((J) >= 10) {                                                 \
                __half2 mu1 = hz, mu2 = hz, vxx = hz, vyy = hz, vxy = hz;    \
                _Pragma("unroll")                                            \
                for (int k = 0; k < 11; ++k) {                               \
                    const int s = ((PHC) + 1 + k) % 11;                      \
                    mu1 = __hfma2(w2[k], ring[0][s], mu1);                   \
                    mu2 = __hfma2(w2[k], ring[1][s], mu2);                   \
                    vxx = __hfma2(w2[k], ring[2][s], vxx);                   \
                    vyy = __hfma2(w2[k], ring[3][s], vyy);                   \
                    vxy = __hfma2(w2[k], ring[4][s], vxy);                   \
                }                                                            \
                const float2 m1 = __half22float2(mu1);                       \
                const float2 m2 = __half22float2(mu2);                       \
                const float2 xx = __half22float2(vxx);                       \
                const float2 yy = __half22float2(vyy);                       \
                const float2 xy = __half22float2(vxy);                       \
                _Pragma("unroll")                                            \
                for (int h = 0; h < 2; ++h) {                                \
                    const float a1 = h ? m1.y : m1.x;                        \
                    const float a2 = h ? m2.y : m2.x;                        \
                    const float bx = h ? xx.y : xx.x;                        \
                    const float by = h ? yy.y : yy.x;                        \
                    const float bz = h ? xy.y : xy.x;                        \
                    const float m11 = a1 * a1, m22 = a2 * a2, m12 = a1 * a2; \
                    const float s1 = bx - m11, s2 = by - m22, s12 = bz - m12;\
                    const float num = (2.f * m12 + C1) * (2.f * s12 + C2);   \
                    const float den = (m11 + m22 + C1) * (s1 + s2 + C2);     \
                    acc = fmaf(num, __builtin_amdgcn_rcpf(den), acc);        \
                }                                                            \
            }                                                                \
            if ((J) + 1 < NIT) STAGE_WRITE((CURC) ^ 1);                      \
        }

    // prologue: stage row 0 into buf 0
    STAGE_LOAD(0);
    STAGE_WRITE(0);

    __half2 ring[5][11];     // x, y, xx, yy, xy — static indices only
    float acc = 0.f;
    const float C1 = 1e-4f, C2 = 9e-4f;
    const __half2 hz = __float2half2_rn(0.f);

    #pragma unroll 1
    for (int jb = 0; jb < 44; jb += 22) {
        // group A: j = jb+ph, jb even -> cur = ph&1 (compile-time)
        #pragma unroll
        for (int ph = 0; ph < 11; ++ph) {
            const int j = jb + ph;
            BODY(j, ph, (ph & 1));
        }
        // group B: j = jb+11+ph -> j%11 = ph, cur = (ph&1)^1 (compile-time)
        #pragma unroll
        for (int ph = 0; ph < 11; ++ph) {
            const int j = jb + 11 + ph;
            BODY(j, ph, ((ph & 1) ^ 1));
        }
    }

    // wave reduction; each wave owns its strip's partial
    #pragma unroll
    for (int off = 32; off > 0; off >>= 1)
        acc += __shfl_down(acc, off, 64);
    if (lane == 0) partial[sid] = acc;
}

__global__ __launch_bounds__(256) void ssim_reduce_kernel(
    const float* __restrict__ partial, float* __restrict__ out)
{
    const int tid = threadIdx.x;
    double s = 0.0;
    for (int i = tid; i < NSTRIP; i += 256) s += (double)partial[i];
    __shared__ double sd[256];
    sd[tid] = s;
    __syncthreads();
    for (int off = 128; off > 0; off >>= 1) {
        if (tid < off) sd[tid] += sd[tid + off];
        __syncthreads();
    }
    if (tid == 0) out[0] = (float)(1.0 - sd[0] / NPIX);
}

extern "C" void kernel_launch(void* const* d_in, const int* in_sizes, int n_in,
                              void* d_out, int out_size, void* d_ws, size_t ws_size,
                              hipStream_t stream) {
    const float* X = (const float*)d_in[0];
    const float* Y = (const float*)d_in[1];
    float* partial = (float*)d_ws;   // NSTRIP floats = 12 KiB
    float* out = (float*)d_out;

    ssim_static_kernel<<<NBLK, 256, 0, stream>>>(X, Y, partial);
    ssim_reduce_kernel<<<1, 256, 0, stream>>>(partial, out);
}

// Round 20
// 58.917 us; speedup vs baseline: 2.2165x; 2.2165x over previous
//
#include <hip/hip_runtime.h>
#include <hip/hip_fp16.h>

// SSIM loss, packed-f16 row-sweep, fully independent waves, ROWS=32.
// FINAL (= round-14 best, 59.6us). Sweep structure: each wave owns a
// 32-row x 128-col output strip; wave-private LDS double-buffered row
// staging (+3 halo words each side); h-pass from 7 consecutive dwords per
// map (stride-1, conflict-free) with alignbit odd-tap views; 5x11 half2
// register ring; v-pass from ring; SSIM formula in f32. ZERO barriers.
//
// Session constraint statement (rounds 15-19 all null/negative):
//  - not memory-bound (13% HBM, L3-resident inputs)
//  - wall = VALU-issue at ~3 waves/SIMD with ~1.6x codegen inflation from
//    unified-file register shuttling of the ring (unsteerable from source:
//    launch_bounds 6/4/2, readfirstlane, ring shrink, static-idx unroll all
//    failed; deep unroll or occupancy caps spill to scratch instead)
//  - MFMA route measured slower (r5: 107us) - staging dwarfs 2.8 GFLOP.

#define ROWS 32
#define NIT  (ROWS + 10)         // 42 staged rows per strip
#define NSTRIP 3072              // 48 img * 16 row-bands * 4 col-strips
#define NBLK  (NSTRIP / 4)       // 768 blocks
#define NPIX  12582912.0

static __device__ __forceinline__ unsigned fun16(unsigned hi, unsigned lo) {
    return __builtin_amdgcn_alignbit(hi, lo, 16);   // v_alignbit_b32
}
static __device__ __forceinline__ unsigned h2u(__half2 v) {
    unsigned u; __builtin_memcpy(&u, &v, 4); return u;
}
static __device__ __forceinline__ __half2 u2h(unsigned u) {
    __half2 v; __builtin_memcpy(&v, &u, 4); return v;
}

__global__ __launch_bounds__(256, 4) void ssim_sweep32_kernel(
    const float* __restrict__ X, const float* __restrict__ Y,
    float* __restrict__ partial)
{
    // [wave][map][dbuf][word]; word i = half2 (x[cs-6+2i], x[cs-5+2i]); 4608 B
    __shared__ unsigned sbw[4][2][2][72];

    const int tid  = threadIdx.x;
    const int lane = tid & 63;
    const int w    = tid >> 6;
    const int sid  = blockIdx.x * 4 + w;
    const int img  = sid >> 6;          // 16 bands * 4 strips = 64
    const int rb   = (sid >> 2) & 15;
    const int cs   = (sid & 3) << 7;    // strip col start
    const int r0   = rb * ROWS;

    const float* __restrict__ Xi = X + (size_t)img * (512 * 512);
    const float* __restrict__ Yi = Y + (size_t)img * (512 * 512);

    // Gaussian weights (matches jnp construction)
    float g[11];
    {
        float s = 0.f;
        #pragma unroll
        for (int i = 0; i < 11; ++i) {
            float d = (float)(i - 5);
            float e = expf(-d * d * (1.0f / 4.5f));
            g[i] = e; s += e;
        }
        float inv = 1.0f / s;
        #pragma unroll
        for (int i = 0; i < 11; ++i) g[i] *= inv;
    }
    __half2 w2[11];
    #pragma unroll
    for (int i = 0; i < 11; ++i) w2[i] = __float2half2_rn(g[i]);

    const int c2 = cs + 2 * lane;       // own 2 cols (always in-image)

    // halo duty: lanes 48-53 -> map0 words {0,1,2,67,68,69}; 56-61 -> map1
    int hq = -1, hm = 0;
    if (lane >= 48 && lane < 54)      { hq = lane - 48; hm = 0; }
    else if (lane >= 56 && lane < 62) { hq = lane - 56; hm = 1; }
    const int  hwd = (hq < 0) ? 0 : (hq < 3 ? hq : 64 + hq);
    const int  hc  = cs - 6 + 2 * hwd;
    const bool hok = (hq >= 0) && ((unsigned)hc < 512u);
    const float* hbase = hm ? Yi : Xi;

    float2 nvx, nvy, nvh;
    #define STAGE_LOAD(J)                                                    \
        {                                                                    \
            int gr = r0 - 5 + (J);                                           \
            nvx = make_float2(0.f, 0.f); nvy = nvx; nvh = nvx;               \
            if ((unsigned)gr < 512u) {                                       \
                const float* xr = Xi + (size_t)gr * 512;                     \
                const float* yr = Yi + (size_t)gr * 512;                     \
                nvx = *(const float2*)(xr + c2);                             \
                nvy = *(const float2*)(yr + c2);                             \
                if (hok) nvh = *(const float2*)(hbase + (size_t)gr * 512 + hc); \
            }                                                                \
        }
    #define STAGE_WRITE(BUF)                                                 \
        {                                                                    \
            sbw[w][0][BUF][3 + lane] = h2u(__floats2half2_rn(nvx.x, nvx.y)); \
            sbw[w][1][BUF][3 + lane] = h2u(__floats2half2_rn(nvy.x, nvy.y)); \
            if (hq >= 0) sbw[w][hm][BUF][hwd] = h2u(__floats2half2_rn(nvh.x, nvh.y)); \
        }

    // prologue: stage row 0 into buf 0
    STAGE_LOAD(0);
    STAGE_WRITE(0);

    __half2 ring[5][11];     // x, y, xx, yy, xy — static indices only
    float acc = 0.f;
    const float C1 = 1e-4f, C2 = 9e-4f;
    const __half2 hz = __float2half2_rn(0.f);

    #pragma unroll 1
    for (int jb = 0; jb < 44; jb += 11) {
        #pragma unroll
        for (int ph = 0; ph < 11; ++ph) {
            const int j = jb + ph;          // j % 11 == ph
            if (j < NIT) {
                const int cur = j & 1, nxt = cur ^ 1;

                // issue next-row global loads early (hide latency)
                if (j + 1 < NIT) STAGE_LOAD(j + 1);

                // read 7-word windows (stride-1, conflict-free)
                unsigned Dx[7], Dy[7];
                #pragma unroll
                for (int k2 = 0; k2 < 7; ++k2) Dx[k2] = sbw[w][0][cur][lane + k2];
                #pragma unroll
                for (int k2 = 0; k2 < 7; ++k2) Dy[k2] = sbw[w][1][cur][lane + k2];

                // h-pass: 11 taps; odd k -> direct word, even k -> alignbit view
                __half2 hx, hy, hxx, hyy, hxy;
                {   // k = 0 initializes (saves the zero-add)
                    const __half2 xk = u2h(fun16(Dx[1], Dx[0]));
                    const __half2 yk = u2h(fun16(Dy[1], Dy[0]));
                    const __half2 wx = __hmul2(w2[0], xk);
                    const __half2 wy = __hmul2(w2[0], yk);
                    hx = wx; hy = wy;
                    hxx = __hmul2(wx, xk);
                    hyy = __hmul2(wy, yk);
                    hxy = __hmul2(wx, yk);
                }
                #pragma unroll
                for (int k = 1; k < 11; ++k) {
                    unsigned ux, uy;
                    if (k & 1) { ux = Dx[(k + 1) >> 1];            uy = Dy[(k + 1) >> 1]; }
                    else       { ux = fun16(Dx[(k >> 1) + 1], Dx[k >> 1]);
                                 uy = fun16(Dy[(k >> 1) + 1], Dy[k >> 1]); }
                    const __half2 xk = u2h(ux), yk = u2h(uy);
                    const __half2 wx = __hmul2(w2[k], xk);
                    const __half2 wy = __hmul2(w2[k], yk);
                    hx  = __hadd2(hx, wx);
                    hy  = __hadd2(hy, wy);
                    hxx = __hfma2(wx, xk, hxx);
                    hyy = __hfma2(wy, yk, hyy);
                    hxy = __hfma2(wx, yk, hxy);
                }
                ring[0][ph] = hx;  ring[1][ph] = hy;
                ring[2][ph] = hxx; ring[3][ph] = hyy; ring[4][ph] = hxy;

                // v-pass from ring (valid once j >= 10)
                if (j >= 10) {
                    __half2 mu1 = hz, mu2 = hz, vxx = hz, vyy = hz, vxy = hz;
                    #pragma unroll
                    for (int k = 0; k < 11; ++k) {
                        const int s = (ph + 1 + k) % 11;
                        mu1 = __hfma2(w2[k], ring[0][s], mu1);
                        mu2 = __hfma2(w2[k], ring[1][s], mu2);
                        vxx = __hfma2(w2[k], ring[2][s], vxx);
                        vyy = __hfma2(w2[k], ring[3][s], vyy);
                        vxy = __hfma2(w2[k], ring[4][s], vxy);
                    }
                    const float2 m1 = __half22float2(mu1);
                    const float2 m2 = __half22float2(mu2);
                    const float2 xx = __half22float2(vxx);
                    const float2 yy = __half22float2(vyy);
                    const float2 xy = __half22float2(vxy);
                    #pragma unroll
                    for (int h = 0; h < 2; ++h) {
                        const float a1 = h ? m1.y : m1.x;
                        const float a2 = h ? m2.y : m2.x;
                        const float bx = h ? xx.y : xx.x;
                        const float by = h ? yy.y : yy.x;
                        const float bz = h ? xy.y : xy.x;
                        const float m11 = a1 * a1, m22 = a2 * a2, m12 = a1 * a2;
                        const float s1 = bx - m11, s2 = by - m22, s12 = bz - m12;
                        const float num = (2.f * m12 + C1) * (2.f * s12 + C2);
                        const float den = (m11 + m22 + C1) * (s1 + s2 + C2);
                        acc = fmaf(num, __builtin_amdgcn_rcpf(den), acc);
                    }
                }

                // write next row into the other buffer (wave-private, no
                // barrier; DS ops are wave-in-order, compiler adds dep waits)
                if (j + 1 < NIT) STAGE_WRITE(nxt);
            }
        }
    }

    // wave reduction; each wave owns its strip's partial
    #pragma unroll
    for (int off = 32; off > 0; off >>= 1)
        acc += __shfl_down(acc, off, 64);
    if (lane == 0) partial[sid] = acc;
}

__global__ __launch_bounds__(256) void ssim_reduce_kernel(
    const float* __restrict__ partial, float* __restrict__ out)
{
    const int tid = threadIdx.x;
    double s = 0.0;
    for (int i = tid; i < NSTRIP; i += 256) s += (double)partial[i];
    __shared__ double sd[256];
    sd[tid] = s;
    __syncthreads();
    for (int off = 128; off > 0; off >>= 1) {
        if (tid < off) sd[tid] += sd[tid + off];
        __syncthreads();
    }
    if (tid == 0) out[0] = (float)(1.0 - sd[0] / NPIX);
}

extern "C" void kernel_launch(void* const* d_in, const int* in_sizes, int n_in,
                              void* d_out, int out_size, void* d_ws, size_t ws_size,
                              hipStream_t stream) {
    const float* X = (const float*)d_in[0];
    const float* Y = (const float*)d_in[1];
    float* partial = (float*)d_ws;   // NSTRIP floats = 12 KiB
    float* out = (float*)d_out;

    ssim_sweep32_kernel<<<NBLK, 256, 0, stream>>>(X, Y, partial);
    ssim_reduce_kernel<<<1, 256, 0, stream>>>(partial, out);
}